// Round 1
// baseline (138.834 us; speedup 1.0000x reference)
//
#include <hip/hip_runtime.h>
#include <stdint.h>

#define B_ 16
#define S_ 2048
#define D_ 512
#define A_ 512
#define M_TOT (B_ * S_)   // 32768 rows

typedef __attribute__((ext_vector_type(4))) float f32x4;
typedef __attribute__((ext_vector_type(8))) short bf16x8;

__device__ inline unsigned short f2bf(float f) {
  union { float f; unsigned int u; } c; c.f = f;
  unsigned int u = c.u;
  unsigned int r = (u + 0x7fffu + ((u >> 16) & 1u)) >> 16;  // RNE
  return (unsigned short)r;
}

// ---------------------------------------------------------------------------
// K0: pack [Wq;Wk] (each [512,512] f32, row = d, col = a) into W_T bf16
// [A=512][Kcat=1024] (row = a, col = d-concat), i.e. B^T layout for the GEMM.
// ---------------------------------------------------------------------------
__global__ __launch_bounds__(256) void k0_pack_w(const float* __restrict__ Wq,
                                                 const float* __restrict__ Wk,
                                                 unsigned short* __restrict__ WT) {
  __shared__ unsigned short tile[64][65];
  int bid = blockIdx.x;
  int dt = bid & 15, at = bid >> 4;     // 16 d-tiles x 8 a-tiles
  int d0 = dt * 64, a0 = at * 64;
  int t = threadIdx.x;
  int col = t & 63, rbase = t >> 6;
#pragma unroll
  for (int r8 = 0; r8 < 16; ++r8) {
    int row = r8 * 4 + rbase;           // local d-concat index
    int dcat = d0 + row;
    float f = (dcat < 512) ? Wq[(size_t)dcat * 512 + a0 + col]
                           : Wk[(size_t)(dcat - 512) * 512 + a0 + col];
    tile[row][col] = f2bf(f);
  }
  __syncthreads();
#pragma unroll
  for (int r8 = 0; r8 < 16; ++r8) {
    int arow = r8 * 4 + rbase;          // local a index
    WT[(size_t)(a0 + arow) * 1024 + d0 + col] = tile[col][arow];
  }
}

// ---------------------------------------------------------------------------
// K1: scores GEMM. partial[cb][row] = sum over 128 cols of tanh(q+k)*Ws.
// 128x128 tile, BK=32, 4 waves, mfma_f32_16x16x32_bf16.
// A = [query|key] fp32 (reg-staged + converted), B = W_T bf16 (ws).
// ---------------------------------------------------------------------------
__global__ __launch_bounds__(256) void k1_scores(
    const float* __restrict__ Q, const float* __restrict__ K,
    const unsigned short* __restrict__ WT, const float* __restrict__ Wsv,
    float* __restrict__ partial) {
  __shared__ unsigned short Al[128][32];   // 8 KiB
  __shared__ unsigned short Bl[128][32];   // 8 KiB
  __shared__ float sc[2][128];
  __shared__ float sws[128];

  int bid = blockIdx.x;
  // XCD-aware mapping: the 4 col-blocks of one row-strip land on one XCD.
  int xcd = bid & 7, idx = bid >> 3;
  int rb = xcd * 32 + (idx >> 2);          // 0..255 row-block
  int cb = idx & 3;                        // 0..3 col-block (128 cols of A=512)

  int t = threadIdx.x;
  int lane = t & 63, wave = t >> 6;
  int wr = wave >> 1, wc = wave & 1;

  if (t < 128) sws[t] = Wsv[cb * 128 + t];

  int row0 = rb * 128;
  int m = t >> 1, half = t & 1;            // A staging: 16 floats / thread

  f32x4 acc[4][4];
#pragma unroll
  for (int i = 0; i < 4; ++i)
#pragma unroll
    for (int j = 0; j < 4; ++j) acc[i][j] = (f32x4){0.f, 0.f, 0.f, 0.f};

  for (int kt = 0; kt < 32; ++kt) {
    int k0 = kt * 32;                      // within concatenated K=1024
    const float* src = (k0 < 512) ? Q : K;
    int kk0 = k0 & 511;
    __syncthreads();
    // ---- A stage: fp32 -> bf16 in regs -> LDS ----
    const float* ap = src + (size_t)(row0 + m) * 512 + kk0 + half * 16;
    float4 f0 = *(const float4*)(ap + 0);
    float4 f1 = *(const float4*)(ap + 4);
    float4 f2 = *(const float4*)(ap + 8);
    float4 f3 = *(const float4*)(ap + 12);
    uint4 wlo, whi;
    wlo.x = f2bf(f0.x) | ((unsigned)f2bf(f0.y) << 16);
    wlo.y = f2bf(f0.z) | ((unsigned)f2bf(f0.w) << 16);
    wlo.z = f2bf(f1.x) | ((unsigned)f2bf(f1.y) << 16);
    wlo.w = f2bf(f1.z) | ((unsigned)f2bf(f1.w) << 16);
    whi.x = f2bf(f2.x) | ((unsigned)f2bf(f2.y) << 16);
    whi.y = f2bf(f2.z) | ((unsigned)f2bf(f2.w) << 16);
    whi.z = f2bf(f3.x) | ((unsigned)f2bf(f3.y) << 16);
    whi.w = f2bf(f3.z) | ((unsigned)f2bf(f3.w) << 16);
    *(uint4*)&Al[m][half * 16]     = wlo;
    *(uint4*)&Al[m][half * 16 + 8] = whi;
    // ---- B stage: bf16 vector copy from W_T ----
    const unsigned short* bp = WT + (size_t)(cb * 128 + m) * 1024 + k0 + half * 16;
    uint4 b0 = *(const uint4*)(bp + 0);
    uint4 b1 = *(const uint4*)(bp + 8);
    *(uint4*)&Bl[m][half * 16]     = b0;
    *(uint4*)&Bl[m][half * 16 + 8] = b1;
    __syncthreads();
    // ---- fragments + MFMA ----
    bf16x8 af[4], bfr[4];
#pragma unroll
    for (int i = 0; i < 4; ++i)
      af[i] = *(const bf16x8*)&Al[wr * 64 + i * 16 + (lane & 15)][(lane >> 4) * 8];
#pragma unroll
    for (int j = 0; j < 4; ++j)
      bfr[j] = *(const bf16x8*)&Bl[wc * 64 + j * 16 + (lane & 15)][(lane >> 4) * 8];
#pragma unroll
    for (int i = 0; i < 4; ++i)
#pragma unroll
      for (int j = 0; j < 4; ++j)
        acc[i][j] = __builtin_amdgcn_mfma_f32_16x16x32_bf16(af[i], bfr[j], acc[i][j], 0, 0, 0);
  }

  // ---- epilogue: tanh, *Ws, reduce over this block's 128 cols ----
  // C/D layout: col = lane&15, row = (lane>>4)*4 + ii  [m89 verified]
#pragma unroll
  for (int i = 0; i < 4; ++i) {
#pragma unroll
    for (int ii = 0; ii < 4; ++ii) {
      float vsum = 0.f;
#pragma unroll
      for (int j = 0; j < 4; ++j)
        vsum += tanhf(acc[i][j][ii]) * sws[wc * 64 + j * 16 + (lane & 15)];
      vsum += __shfl_xor(vsum, 1);
      vsum += __shfl_xor(vsum, 2);
      vsum += __shfl_xor(vsum, 4);
      vsum += __shfl_xor(vsum, 8);
      if ((lane & 15) == 0)
        sc[wc][wr * 64 + i * 16 + (lane >> 4) * 4 + ii] = vsum;
    }
  }
  __syncthreads();
  if (t < 128)
    partial[(size_t)cb * M_TOT + row0 + t] = sc[0][t] + sc[1][t];
}

// ---------------------------------------------------------------------------
// K2: softmax over S=2048 per batch. Sums the 4 col-block partials.
// Writes attention weights (output #2) to d_out + B*A.
// ---------------------------------------------------------------------------
__global__ __launch_bounds__(256) void k2_softmax(const float* __restrict__ partial,
                                                  float* __restrict__ outw) {
  int b = blockIdx.x, t = threadIdx.x;
  int lane = t & 63, wave = t >> 6;
  __shared__ float red[4], red2[4];
  float v[8];
  float mx = -1e30f;
#pragma unroll
  for (int e = 0; e < 8; ++e) {
    size_t o = (size_t)b * S_ + e * 256 + t;
    float p = partial[o] + partial[M_TOT + o] + partial[2 * M_TOT + o] + partial[3 * M_TOT + o];
    v[e] = p;
    mx = fmaxf(mx, p);
  }
  for (int off = 1; off < 64; off <<= 1) mx = fmaxf(mx, __shfl_xor(mx, off));
  if (lane == 0) red[wave] = mx;
  __syncthreads();
  mx = fmaxf(fmaxf(red[0], red[1]), fmaxf(red[2], red[3]));
  float sum = 0.f;
#pragma unroll
  for (int e = 0; e < 8; ++e) { v[e] = expf(v[e] - mx); sum += v[e]; }
  for (int off = 1; off < 64; off <<= 1) sum += __shfl_xor(sum, off);
  if (lane == 0) red2[wave] = sum;
  __syncthreads();
  sum = red2[0] + red2[1] + red2[2] + red2[3];
  float inv = 1.f / sum;
#pragma unroll
  for (int e = 0; e < 8; ++e)
    outw[(size_t)b * S_ + e * 256 + t] = v[e] * inv;
}

// ---------------------------------------------------------------------------
// K3: u_part[sc][b][d] = sum over 128 s of w[b,s]*value[b,s,d]. Full fp32.
// grid = b(16) * dchunk(2) * schunk(16) = 512 blocks.
// ---------------------------------------------------------------------------
__global__ __launch_bounds__(256) void k3_vsum(const float* __restrict__ value,
                                               const float* __restrict__ w,
                                               float* __restrict__ upart) {
  int bid = blockIdx.x;
  int schunk = bid & 15, dchunk = (bid >> 4) & 1, b = bid >> 5;
  int t = threadIdx.x;
  __shared__ float wl[128];
  int s0 = schunk * 128;
  if (t < 128) wl[t] = w[(size_t)b * S_ + s0 + t];
  __syncthreads();
  const float* vp = value + ((size_t)b * S_ + s0) * 512 + dchunk * 256 + t;
  float a0 = 0.f, a1 = 0.f, a2 = 0.f, a3 = 0.f;
  for (int s = 0; s < 128; s += 4) {
    a0 += wl[s + 0] * vp[(size_t)(s + 0) * 512];
    a1 += wl[s + 1] * vp[(size_t)(s + 1) * 512];
    a2 += wl[s + 2] * vp[(size_t)(s + 2) * 512];
    a3 += wl[s + 3] * vp[(size_t)(s + 3) * 512];
  }
  upart[(size_t)(schunk * 16 + b) * 512 + dchunk * 256 + t] = (a0 + a1) + (a2 + a3);
}

// ---------------------------------------------------------------------------
// K4: context[b,a] = sum_d u[b,d] * Wv[d,a], u = sum of 16 partials. fp32.
// ---------------------------------------------------------------------------
__global__ __launch_bounds__(512) void k4_ctx(const float* __restrict__ upart,
                                              const float* __restrict__ Wv,
                                              float* __restrict__ out) {
  int b = blockIdx.x, t = threadIdx.x;   // t = a, 512 threads
  __shared__ float ul[512];
  float u = 0.f;
#pragma unroll
  for (int c = 0; c < 16; ++c) u += upart[(size_t)(c * 16 + b) * 512 + t];
  ul[t] = u;
  __syncthreads();
  float acc = 0.f;
#pragma unroll 8
  for (int d = 0; d < 512; ++d) acc += ul[d] * Wv[(size_t)d * 512 + t];
  out[(size_t)b * 512 + t] = acc;
}

// ---------------------------------------------------------------------------
extern "C" void kernel_launch(void* const* d_in, const int* in_sizes, int n_in,
                              void* d_out, int out_size, void* d_ws, size_t ws_size,
                              hipStream_t stream) {
  const float* Q  = (const float*)d_in[0];
  const float* Kk = (const float*)d_in[1];
  const float* V  = (const float*)d_in[2];
  const float* Wq = (const float*)d_in[3];
  const float* Wk = (const float*)d_in[4];
  const float* Wv = (const float*)d_in[5];
  const float* Ws = (const float*)d_in[6];
  float* out = (float*)d_out;

  char* ws = (char*)d_ws;
  unsigned short* WT = (unsigned short*)ws;                        // 1 MiB: W_T bf16 [512][1024]
  float* partial = (float*)(ws + (1 << 20));                       // 512 KiB: [4][32768]
  float* upart   = (float*)(ws + (1 << 20) + (512 << 10));         // 512 KiB: [16][16][512]

  float* outw = out + B_ * A_;   // attention weights region [B*S]

  k0_pack_w<<<dim3(128), dim3(256), 0, stream>>>(Wq, Wk, WT);
  k1_scores<<<dim3(1024), dim3(256), 0, stream>>>(Q, Kk, WT, Ws, partial);
  k2_softmax<<<dim3(16), dim3(256), 0, stream>>>(partial, outw);
  k3_vsum<<<dim3(512), dim3(256), 0, stream>>>(V, outw, upart);
  k4_ctx<<<dim3(16), dim3(512), 0, stream>>>(upart, Wv, out);
}

// Round 2
// 103.288 us; speedup vs baseline: 1.3442x; 1.3442x over previous
//
#include <hip/hip_runtime.h>
#include <stdint.h>

#define B_ 16
#define S_ 2048
#define D_ 512
#define A_ 512
#define M_TOT (B_ * S_)   // 32768 rows

typedef __attribute__((ext_vector_type(4))) float f32x4;
typedef __attribute__((ext_vector_type(8))) short bf16x8;

__device__ inline unsigned short f2bf(float f) {
  union { float f; unsigned int u; } c; c.f = f;
  unsigned int u = c.u;
  unsigned int r = (u + 0x7fffu + ((u >> 16) & 1u)) >> 16;  // RNE
  return (unsigned short)r;
}

__device__ inline float fast_tanh(float x) {
  // tanh(x) = 1 - 2/(e^{2x}+1); saturates correctly at +/-inf.
  float e = __expf(2.0f * x);
  return 1.0f - 2.0f * __builtin_amdgcn_rcpf(e + 1.0f);
}

__device__ inline void gload_lds16(const void* g, void* l) {
  __builtin_amdgcn_global_load_lds((const __attribute__((address_space(1))) void*)g,
                                   (__attribute__((address_space(3))) void*)l, 16, 0, 0);
}

// ---------------------------------------------------------------------------
// K0: pack [Wq;Wk] (each [512,512] f32, row=d, col=a) into WT bf16
// [A=512][Kcat=1024] (row=a, col=d-concat), i.e. B^T layout for the GEMM.
// ---------------------------------------------------------------------------
__global__ __launch_bounds__(256) void k0_pack_w(const float* __restrict__ Wq,
                                                 const float* __restrict__ Wk,
                                                 unsigned short* __restrict__ WT) {
  __shared__ unsigned short tile[64][65];
  int bid = blockIdx.x;
  int dt = bid & 15, at = bid >> 4;     // 16 d-tiles x 8 a-tiles
  int d0 = dt * 64, a0 = at * 64;
  int t = threadIdx.x;
  int col = t & 63, rbase = t >> 6;
#pragma unroll
  for (int r8 = 0; r8 < 16; ++r8) {
    int row = r8 * 4 + rbase;           // local d-concat index
    int dcat = d0 + row;
    float f = (dcat < 512) ? Wq[(size_t)dcat * 512 + a0 + col]
                           : Wk[(size_t)(dcat - 512) * 512 + a0 + col];
    tile[row][col] = f2bf(f);
  }
  __syncthreads();
#pragma unroll
  for (int r8 = 0; r8 < 16; ++r8) {
    int arow = r8 * 4 + rbase;          // local a index
    WT[(size_t)(a0 + arow) * 1024 + d0 + col] = tile[col][arow];
  }
}

// ---------------------------------------------------------------------------
// K1: scores. One block = 128 rows x FULL N=512. BM=128 BN=512 BK=64,
// 8 waves (1 M x 8 N), mfma_f32_16x16x32_bf16.
// A (query|key fp32) converted to bf16 ONCE, XOR-swizzled LDS (T2).
// B staged via global_load_lds w=16 with pre-swizzled global source (m173).
// Epilogue: fast-tanh * Ws, cross-lane reduce, one score per row.
// LDS swizzle: chunk(row, dslot) holds canonical (row, dslot ^ (row&7)),
// 16B chunks, row stride 128B.
// ---------------------------------------------------------------------------
__global__ __launch_bounds__(512, 2) void k1_scores(
    const float* __restrict__ Q, const float* __restrict__ K,
    const unsigned short* __restrict__ WT, const float* __restrict__ Wsv,
    float* __restrict__ score) {
  __shared__ unsigned short Al[128 * 64];   // 16 KiB (swizzled)
  __shared__ unsigned short Bl[512 * 64];   // 64 KiB (swizzled)
  __shared__ float sws[512];
  __shared__ float scw[8][128];

  const int t = threadIdx.x;
  const int lane = t & 63, w = t >> 6;
  const int frow = lane & 15;       // fragment row-in-16
  const int fsl = lane >> 4;        // fragment 16B slot-in-kstep (0..3)
  const int row0 = (int)blockIdx.x * 128;

  sws[t] = Wsv[t];

  // A staging geometry: thread covers row am, canonical slots as0, as0+1
  const int am = t >> 2;
  const int as0 = (t & 3) * 2;

  f32x4 acc[8][4];
#pragma unroll
  for (int m = 0; m < 8; ++m)
#pragma unroll
    for (int n = 0; n < 4; ++n) acc[m][n] = (f32x4){0.f, 0.f, 0.f, 0.f};

  auto stageA = [&](int kt) {
    int k0 = kt * 64;
    const float* src = (k0 < 512) ? Q : K;
    int kk = (k0 & 511) + as0 * 8;
    const float* ap = src + (size_t)(row0 + am) * 512 + kk;
    float4 f0 = *(const float4*)(ap + 0);
    float4 f1 = *(const float4*)(ap + 4);
    float4 f2 = *(const float4*)(ap + 8);
    float4 f3 = *(const float4*)(ap + 12);
    uint4 c0, c1;
    c0.x = f2bf(f0.x) | ((unsigned)f2bf(f0.y) << 16);
    c0.y = f2bf(f0.z) | ((unsigned)f2bf(f0.w) << 16);
    c0.z = f2bf(f1.x) | ((unsigned)f2bf(f1.y) << 16);
    c0.w = f2bf(f1.z) | ((unsigned)f2bf(f1.w) << 16);
    c1.x = f2bf(f2.x) | ((unsigned)f2bf(f2.y) << 16);
    c1.y = f2bf(f2.z) | ((unsigned)f2bf(f2.w) << 16);
    c1.z = f2bf(f3.x) | ((unsigned)f2bf(f3.y) << 16);
    c1.w = f2bf(f3.z) | ((unsigned)f2bf(f3.w) << 16);
    int d0 = (as0 ^ (am & 7)), d1 = ((as0 + 1) ^ (am & 7));
    *(uint4*)((char*)Al + am * 128 + d0 * 16) = c0;
    *(uint4*)((char*)Al + am * 128 + d1 * 16) = c1;
  };

  auto stageB = [&](int kt) {
    int k0 = kt * 64;
#pragma unroll
    for (int q = 0; q < 8; ++q) {
      int p = (w * 8 + q) * 64 + lane;       // LDS chunk index
      int row = p >> 3;
      int sl = (p & 7) ^ (row & 7);          // pre-swizzled source slot
      const char* g = (const char*)WT + (size_t)row * 2048 + k0 * 2 + sl * 16;
      char* l = (char*)Bl + (size_t)(w * 8 + q) * 1024;   // wave-uniform base
      gload_lds16(g, l);
    }
  };

  stageA(0);
  stageB(0);

  for (int kt = 0; kt < 16; ++kt) {
    __syncthreads();                      // staging of tile kt visible
    // ---- ks = 0 fragments + MFMA ----
    bf16x8 a0[8], b0[4];
#pragma unroll
    for (int m = 0; m < 8; ++m) {
      int row = m * 16 + frow;
      int sl = fsl ^ (row & 7);
      a0[m] = *(const bf16x8*)((const char*)Al + row * 128 + sl * 16);
    }
#pragma unroll
    for (int n = 0; n < 4; ++n) {
      int row = w * 64 + n * 16 + frow;
      int sl = fsl ^ (row & 7);
      b0[n] = *(const bf16x8*)((const char*)Bl + row * 128 + sl * 16);
    }
#pragma unroll
    for (int m = 0; m < 8; ++m)
#pragma unroll
      for (int n = 0; n < 4; ++n)
        acc[m][n] = __builtin_amdgcn_mfma_f32_16x16x32_bf16(a0[m], b0[n], acc[m][n], 0, 0, 0);
    // ---- ks = 1 fragments ----
    bf16x8 a1[8], b1[4];
#pragma unroll
    for (int m = 0; m < 8; ++m) {
      int row = m * 16 + frow;
      int sl = (4 + fsl) ^ (row & 7);
      a1[m] = *(const bf16x8*)((const char*)Al + row * 128 + sl * 16);
    }
#pragma unroll
    for (int n = 0; n < 4; ++n) {
      int row = w * 64 + n * 16 + frow;
      int sl = (4 + fsl) ^ (row & 7);
      b1[n] = *(const bf16x8*)((const char*)Bl + row * 128 + sl * 16);
    }
    __syncthreads();                      // all reads of tile kt done
    if (kt < 15) { stageA(kt + 1); stageB(kt + 1); }  // overlaps ks=1 MFMAs
#pragma unroll
    for (int m = 0; m < 8; ++m)
#pragma unroll
      for (int n = 0; n < 4; ++n)
        acc[m][n] = __builtin_amdgcn_mfma_f32_16x16x32_bf16(a1[m], b1[n], acc[m][n], 0, 0, 0);
  }

  // ---- epilogue: tanh * Ws, reduce over all 512 cols ----
  // C/D: col = lane&15 (+n*16+w*64), row = (lane>>4)*4 + ii (+m*16)
#pragma unroll
  for (int m = 0; m < 8; ++m) {
#pragma unroll
    for (int ii = 0; ii < 4; ++ii) {
      float s = 0.f;
#pragma unroll
      for (int n = 0; n < 4; ++n)
        s += fast_tanh(acc[m][n][ii]) * sws[w * 64 + n * 16 + frow];
      s += __shfl_xor(s, 1);
      s += __shfl_xor(s, 2);
      s += __shfl_xor(s, 4);
      s += __shfl_xor(s, 8);
      if (frow == 0) scw[w][m * 16 + fsl * 4 + ii] = s;
    }
  }
  __syncthreads();
  if (t < 128) {
    float s = 0.f;
#pragma unroll
    for (int ww = 0; ww < 8; ++ww) s += scw[ww][t];
    score[row0 + t] = s;
  }
}

// ---------------------------------------------------------------------------
// K2: softmax over S=2048 per batch. Writes attention weights to d_out+B*A.
// ---------------------------------------------------------------------------
__global__ __launch_bounds__(256) void k2_softmax(const float* __restrict__ score,
                                                  float* __restrict__ outw) {
  int b = blockIdx.x, t = threadIdx.x;
  int lane = t & 63, wave = t >> 6;
  __shared__ float red[4], red2[4];
  float v[8];
  float mx = -1e30f;
#pragma unroll
  for (int e = 0; e < 8; ++e) {
    float p = score[(size_t)b * S_ + e * 256 + t];
    v[e] = p;
    mx = fmaxf(mx, p);
  }
  for (int off = 1; off < 64; off <<= 1) mx = fmaxf(mx, __shfl_xor(mx, off));
  if (lane == 0) red[wave] = mx;
  __syncthreads();
  mx = fmaxf(fmaxf(red[0], red[1]), fmaxf(red[2], red[3]));
  float sum = 0.f;
#pragma unroll
  for (int e = 0; e < 8; ++e) { v[e] = expf(v[e] - mx); sum += v[e]; }
  for (int off = 1; off < 64; off <<= 1) sum += __shfl_xor(sum, off);
  if (lane == 0) red2[wave] = sum;
  __syncthreads();
  sum = red2[0] + red2[1] + red2[2] + red2[3];
  float inv = 1.f / sum;
#pragma unroll
  for (int e = 0; e < 8; ++e)
    outw[(size_t)b * S_ + e * 256 + t] = v[e] * inv;
}

// ---------------------------------------------------------------------------
// K3: u_part[sc][b][d] = sum over 128 s of w[b,s]*value[b,s,d]. Full fp32.
// ---------------------------------------------------------------------------
__global__ __launch_bounds__(256) void k3_vsum(const float* __restrict__ value,
                                               const float* __restrict__ w,
                                               float* __restrict__ upart) {
  int bid = blockIdx.x;
  int schunk = bid & 15, dchunk = (bid >> 4) & 1, b = bid >> 5;
  int t = threadIdx.x;
  __shared__ float wl[128];
  int s0 = schunk * 128;
  if (t < 128) wl[t] = w[(size_t)b * S_ + s0 + t];
  __syncthreads();
  const float* vp = value + ((size_t)b * S_ + s0) * 512 + dchunk * 256 + t;
  float a0 = 0.f, a1 = 0.f, a2 = 0.f, a3 = 0.f;
  for (int s = 0; s < 128; s += 4) {
    a0 += wl[s + 0] * vp[(size_t)(s + 0) * 512];
    a1 += wl[s + 1] * vp[(size_t)(s + 1) * 512];
    a2 += wl[s + 2] * vp[(size_t)(s + 2) * 512];
    a3 += wl[s + 3] * vp[(size_t)(s + 3) * 512];
  }
  upart[(size_t)(schunk * 16 + b) * 512 + dchunk * 256 + t] = (a0 + a1) + (a2 + a3);
}

// ---------------------------------------------------------------------------
// K4: context[b,a] = sum_d u[b,d] * Wv[d,a]. fp32.
// ---------------------------------------------------------------------------
__global__ __launch_bounds__(512) void k4_ctx(const float* __restrict__ upart,
                                              const float* __restrict__ Wv,
                                              float* __restrict__ out) {
  int b = blockIdx.x, t = threadIdx.x;   // t = a
  __shared__ float ul[512];
  float u = 0.f;
#pragma unroll
  for (int c = 0; c < 16; ++c) u += upart[(size_t)(c * 16 + b) * 512 + t];
  ul[t] = u;
  __syncthreads();
  float acc = 0.f;
#pragma unroll 8
  for (int d = 0; d < 512; ++d) acc += ul[d] * Wv[(size_t)d * 512 + t];
  out[(size_t)b * 512 + t] = acc;
}

// ---------------------------------------------------------------------------
extern "C" void kernel_launch(void* const* d_in, const int* in_sizes, int n_in,
                              void* d_out, int out_size, void* d_ws, size_t ws_size,
                              hipStream_t stream) {
  const float* Q  = (const float*)d_in[0];
  const float* Kk = (const float*)d_in[1];
  const float* V  = (const float*)d_in[2];
  const float* Wq = (const float*)d_in[3];
  const float* Wk = (const float*)d_in[4];
  const float* Wv = (const float*)d_in[5];
  const float* Ws = (const float*)d_in[6];
  float* out = (float*)d_out;

  char* ws = (char*)d_ws;
  unsigned short* WT = (unsigned short*)ws;                        // 1 MiB: WT bf16 [512][1024]
  float* score = (float*)(ws + (1 << 20));                         // 128 KiB: [32768]
  float* upart = (float*)(ws + (1 << 20) + (512 << 10));           // 512 KiB: [16][16][512]

  float* outw = out + B_ * A_;   // attention weights region [B*S]

  k0_pack_w<<<dim3(128), dim3(256), 0, stream>>>(Wq, Wk, WT);
  k1_scores<<<dim3(256), dim3(512), 0, stream>>>(Q, Kk, WT, Ws, score);
  k2_softmax<<<dim3(16), dim3(256), 0, stream>>>(score, outw);
  k3_vsum<<<dim3(512), dim3(256), 0, stream>>>(V, outw, upart);
  k4_ctx<<<dim3(16), dim3(512), 0, stream>>>(upart, Wv, out);
}

// Round 3
// 101.522 us; speedup vs baseline: 1.3675x; 1.0174x over previous
//
#include <hip/hip_runtime.h>
#include <stdint.h>

#define B_ 16
#define S_ 2048
#define D_ 512
#define A_ 512
#define M_TOT (B_ * S_)   // 32768 rows

typedef __attribute__((ext_vector_type(4))) float f32x4;
typedef __attribute__((ext_vector_type(8))) short bf16x8;

__device__ inline unsigned short f2bf(float f) {
  union { float f; unsigned int u; } c; c.f = f;
  unsigned int u = c.u;
  unsigned int r = (u + 0x7fffu + ((u >> 16) & 1u)) >> 16;  // RNE
  return (unsigned short)r;
}

__device__ inline float fast_tanh(float x) {
  float e = __expf(2.0f * x);
  return 1.0f - 2.0f * __builtin_amdgcn_rcpf(e + 1.0f);
}

__device__ inline void gload_lds16(const void* g, void* l) {
  __builtin_amdgcn_global_load_lds((const __attribute__((address_space(1))) void*)g,
                                   (__attribute__((address_space(3))) void*)l, 16, 0, 0);
}

// ---------------------------------------------------------------------------
// K0: pack [Wq;Wk] (each [512,512] f32, row=d, col=a) into WT bf16
// [A=512][Kcat=1024] (row=a, col=d-concat), i.e. B^T layout for the GEMM.
// ---------------------------------------------------------------------------
__global__ __launch_bounds__(256) void k0_pack_w(const float* __restrict__ Wq,
                                                 const float* __restrict__ Wk,
                                                 unsigned short* __restrict__ WT) {
  __shared__ unsigned short tile[64][65];
  int bid = blockIdx.x;
  int dt = bid & 15, at = bid >> 4;
  int d0 = dt * 64, a0 = at * 64;
  int t = threadIdx.x;
  int col = t & 63, rbase = t >> 6;
#pragma unroll
  for (int r8 = 0; r8 < 16; ++r8) {
    int row = r8 * 4 + rbase;
    int dcat = d0 + row;
    float f = (dcat < 512) ? Wq[(size_t)dcat * 512 + a0 + col]
                           : Wk[(size_t)(dcat - 512) * 512 + a0 + col];
    tile[row][col] = f2bf(f);
  }
  __syncthreads();
#pragma unroll
  for (int r8 = 0; r8 < 16; ++r8) {
    int arow = r8 * 4 + rbase;
    WT[(size_t)(a0 + arow) * 1024 + d0 + col] = tile[col][arow];
  }
}

// ---------------------------------------------------------------------------
// K1: scores. BM=64, BN=512 (full N), BK=32, NT=32 k-tiles.
// 512 threads = 8 waves, wave w owns cols w*64 (4x4 16x16x32 frags).
// Double-buffered LDS, ONE barrier per k-tile.
// A: fp32 -> reg (issued 2 tiles ahead) -> bf16 convert -> swizzled LDS.
// B: global_load_lds w=16 from pre-swizzled WT source (issued 1 tile ahead).
// Swizzle: 64B rows, 4x16B chunks, chunk' = chunk ^ ((row>>1)&3).
// Epilogue: fast-tanh * Ws + cross-lane reduce -> one score per row.
// ---------------------------------------------------------------------------
__global__ __launch_bounds__(512, 4) void k1_scores(
    const float* __restrict__ Q, const float* __restrict__ K,
    const unsigned short* __restrict__ WT, const float* __restrict__ Wsv,
    float* __restrict__ score) {
  __shared__ unsigned short Al[2][64 * 32];    // 2 x 4 KiB
  __shared__ unsigned short Bl[2][512 * 32];   // 2 x 32 KiB
  __shared__ float sws[512];
  __shared__ float scw[8][64];

  const int t = threadIdx.x;
  const int lane = t & 63, w = t >> 6;
  const int frow = lane & 15, fsl = lane >> 4;
  const int row0 = (int)blockIdx.x * 64;

  sws[t] = Wsv[t];

  // A staging geometry: thread loads row ar, 4 floats at col ak.
  const int ar = t >> 3, ak = (t & 7) * 4;
  const int wchunk = (t & 7) >> 1;
  const int wbyte = ar * 64 + ((wchunk ^ ((ar >> 1) & 3)) * 16) + (t & 1) * 8;

  float4 areg[2];

  auto issueA = [&](int kt, int j) {
    int kcat = kt * 32;
    const float* src = (kcat < 512) ? Q : K;
    areg[j] = *(const float4*)(src + (size_t)(row0 + ar) * 512 + (kcat & 511) + ak);
  };
  auto stageAW = [&](int j) {
    float4 f = areg[j];
    uint2 d;
    d.x = f2bf(f.x) | ((unsigned)f2bf(f.y) << 16);
    d.y = f2bf(f.z) | ((unsigned)f2bf(f.w) << 16);
    *(uint2*)((char*)&Al[j][0] + wbyte) = d;
  };
  auto stageB = [&](int kt) {
    int j = kt & 1;
    int kb = kt * 64;            // byte offset within a WT row
#pragma unroll
    for (int q = 0; q < 4; ++q) {
      int p = (w * 4 + q) * 64 + lane;       // 16B-chunk index
      int row = p >> 2;
      int sl = (p & 3) ^ ((row >> 1) & 3);   // inverse-swizzled source slot
      const char* g = (const char*)WT + (size_t)row * 2048 + kb + sl * 16;
      char* l = (char*)&Bl[j][0] + (size_t)(w * 4 + q) * 1024;  // wave-uniform
      gload_lds16(g, l);
    }
  };

  f32x4 acc[4][4];
#pragma unroll
  for (int m = 0; m < 4; ++m)
#pragma unroll
    for (int n = 0; n < 4; ++n) acc[m][n] = (f32x4){0.f, 0.f, 0.f, 0.f};

  // Prologue: tile 0 fully staged; A(1) in flight.
  issueA(0, 0);
  stageAW(0);
  stageB(0);
  issueA(1, 1);

#pragma unroll 2
  for (int kt = 0; kt < 32; ++kt) {
    const int cur = kt & 1;
    __syncthreads();                          // buf[cur] ready; buf[cur^1] free
    if (kt + 2 < 32) issueA(kt + 2, cur);     // issue early (full-phase cover)
    if (kt + 1 < 32) { stageAW(cur ^ 1); stageB(kt + 1); }
    bf16x8 af[4], bfr[4];
    const int ch = (fsl ^ ((frow >> 1) & 3)) * 16;
#pragma unroll
    for (int m = 0; m < 4; ++m)
      af[m] = *(const bf16x8*)((const char*)&Al[cur][0] + (m * 16 + frow) * 64 + ch);
#pragma unroll
    for (int n = 0; n < 4; ++n)
      bfr[n] = *(const bf16x8*)((const char*)&Bl[cur][0] + (w * 64 + n * 16 + frow) * 64 + ch);
#pragma unroll
    for (int m = 0; m < 4; ++m)
#pragma unroll
      for (int n = 0; n < 4; ++n)
        acc[m][n] = __builtin_amdgcn_mfma_f32_16x16x32_bf16(af[m], bfr[n], acc[m][n], 0, 0, 0);
  }

  // Epilogue: C/D col = frow (+n*16+w*64), row = fsl*4 + ii (+m*16).
#pragma unroll
  for (int m = 0; m < 4; ++m) {
#pragma unroll
    for (int ii = 0; ii < 4; ++ii) {
      float s = 0.f;
#pragma unroll
      for (int n = 0; n < 4; ++n)
        s += fast_tanh(acc[m][n][ii]) * sws[w * 64 + n * 16 + frow];
      s += __shfl_xor(s, 1);
      s += __shfl_xor(s, 2);
      s += __shfl_xor(s, 4);
      s += __shfl_xor(s, 8);
      if (frow == 0) scw[w][m * 16 + fsl * 4 + ii] = s;
    }
  }
  __syncthreads();
  if (t < 64) {
    float s = 0.f;
#pragma unroll
    for (int ww = 0; ww < 8; ++ww) s += scw[ww][t];
    score[row0 + t] = s;
  }
}

// ---------------------------------------------------------------------------
// K2: softmax over S=2048 per batch. Writes attention weights to d_out+B*A.
// ---------------------------------------------------------------------------
__global__ __launch_bounds__(256) void k2_softmax(const float* __restrict__ score,
                                                  float* __restrict__ outw) {
  int b = blockIdx.x, t = threadIdx.x;
  int lane = t & 63, wave = t >> 6;
  __shared__ float red[4], red2[4];
  float v[8];
  float mx = -1e30f;
#pragma unroll
  for (int e = 0; e < 8; ++e) {
    float p = score[(size_t)b * S_ + e * 256 + t];
    v[e] = p;
    mx = fmaxf(mx, p);
  }
  for (int off = 1; off < 64; off <<= 1) mx = fmaxf(mx, __shfl_xor(mx, off));
  if (lane == 0) red[wave] = mx;
  __syncthreads();
  mx = fmaxf(fmaxf(red[0], red[1]), fmaxf(red[2], red[3]));
  float sum = 0.f;
#pragma unroll
  for (int e = 0; e < 8; ++e) { v[e] = expf(v[e] - mx); sum += v[e]; }
  for (int off = 1; off < 64; off <<= 1) sum += __shfl_xor(sum, off);
  if (lane == 0) red2[wave] = sum;
  __syncthreads();
  sum = red2[0] + red2[1] + red2[2] + red2[3];
  float inv = 1.f / sum;
#pragma unroll
  for (int e = 0; e < 8; ++e)
    outw[(size_t)b * S_ + e * 256 + t] = v[e] * inv;
}

// ---------------------------------------------------------------------------
// K3: u_part[sc][b][d-half] = sum over 128 s of w[b,s]*value[b,s,d]. fp32.
// grid = dh(2) x sc(16) x b(16) = 512 blocks, 256 threads, float4 loads.
// ---------------------------------------------------------------------------
__global__ __launch_bounds__(256) void k3_vsum(const float* __restrict__ value,
                                               const float* __restrict__ w,
                                               float* __restrict__ upart) {
  int bid = blockIdx.x;
  int dh = bid & 1, sc = (bid >> 1) & 15, b = bid >> 5;
  int t = threadIdx.x;
  int dg = t & 63, sg = t >> 6;            // 64 d-groups x 4 s-groups
  __shared__ float wl[128];
  __shared__ f32x4 red[4][64];
  int s0 = sc * 128;
  if (t < 128) wl[t] = w[(size_t)b * S_ + s0 + t];
  __syncthreads();
  const float* vp = value + ((size_t)b * S_ + s0) * 512 + dh * 256 + dg * 4;
  f32x4 a = (f32x4){0.f, 0.f, 0.f, 0.f};
  for (int s = sg; s < 128; s += 4) {
    float4 v4 = *(const float4*)(vp + (size_t)s * 512);
    float ws = wl[s];
    a[0] += ws * v4.x; a[1] += ws * v4.y; a[2] += ws * v4.z; a[3] += ws * v4.w;
  }
  red[sg][dg] = a;
  __syncthreads();
  if (sg == 0) {
    f32x4 r = red[0][dg] + red[1][dg] + red[2][dg] + red[3][dg];
    float* dst = upart + (size_t)(sc * 16 + b) * 512 + dh * 256 + dg * 4;
    dst[0] = r[0]; dst[1] = r[1]; dst[2] = r[2]; dst[3] = r[3];
  }
}

// ---------------------------------------------------------------------------
// K4: context[b,a] = sum_d u[b,d] * Wv[d,a]. fp32.
// ---------------------------------------------------------------------------
__global__ __launch_bounds__(512) void k4_ctx(const float* __restrict__ upart,
                                              const float* __restrict__ Wv,
                                              float* __restrict__ out) {
  int b = blockIdx.x, t = threadIdx.x;   // t = a
  __shared__ float ul[512];
  float u = 0.f;
#pragma unroll
  for (int c = 0; c < 16; ++c) u += upart[(size_t)(c * 16 + b) * 512 + t];
  ul[t] = u;
  __syncthreads();
  float acc = 0.f;
#pragma unroll 8
  for (int d = 0; d < 512; ++d) acc += ul[d] * Wv[(size_t)d * 512 + t];
  out[(size_t)b * 512 + t] = acc;
}

// ---------------------------------------------------------------------------
extern "C" void kernel_launch(void* const* d_in, const int* in_sizes, int n_in,
                              void* d_out, int out_size, void* d_ws, size_t ws_size,
                              hipStream_t stream) {
  const float* Q  = (const float*)d_in[0];
  const float* Kk = (const float*)d_in[1];
  const float* V  = (const float*)d_in[2];
  const float* Wq = (const float*)d_in[3];
  const float* Wk = (const float*)d_in[4];
  const float* Wv = (const float*)d_in[5];
  const float* Ws = (const float*)d_in[6];
  float* out = (float*)d_out;

  char* ws = (char*)d_ws;
  unsigned short* WT = (unsigned short*)ws;                        // 1 MiB
  float* score = (float*)(ws + (1 << 20));                         // 128 KiB
  float* upart = (float*)(ws + (1 << 20) + (512 << 10));           // 512 KiB

  float* outw = out + B_ * A_;   // attention weights region [B*S]

  k0_pack_w<<<dim3(128), dim3(256), 0, stream>>>(Wq, Wk, WT);
  k1_scores<<<dim3(512), dim3(512), 0, stream>>>(Q, Kk, WT, Ws, score);
  k2_softmax<<<dim3(16), dim3(256), 0, stream>>>(score, outw);
  k3_vsum<<<dim3(512), dim3(256), 0, stream>>>(V, outw, upart);
  k4_ctx<<<dim3(16), dim3(512), 0, stream>>>(upart, Wv, out);
}

// Round 4
// 97.066 us; speedup vs baseline: 1.4303x; 1.0459x over previous
//
#include <hip/hip_runtime.h>
#include <stdint.h>

#define B_ 16
#define S_ 2048
#define D_ 512
#define A_ 512

typedef __attribute__((ext_vector_type(4))) float f32x4;
typedef __attribute__((ext_vector_type(8))) short bf16x8;

__device__ inline unsigned short f2bf(float f) {
  union { float f; unsigned int u; } c; c.f = f;
  unsigned int u = c.u;
  unsigned int r = (u + 0x7fffu + ((u >> 16) & 1u)) >> 16;  // RNE
  return (unsigned short)r;
}

__device__ inline float fast_tanh(float x) {
  float e = __expf(2.0f * x);
  return 1.0f - 2.0f * __builtin_amdgcn_rcpf(e + 1.0f);
}

__device__ inline void gload_lds16(const void* g, void* l) {
  __builtin_amdgcn_global_load_lds((const __attribute__((address_space(1))) void*)g,
                                   (__attribute__((address_space(3))) void*)l, 16, 0, 0);
}

// ---------------------------------------------------------------------------
// K0: pack [Wq;Wk] (each [512,512] f32, row=d, col=a) into WT bf16
// [A=512][Kcat=1024] (row=a, col=d-concat), i.e. B^T layout for the GEMM.
// ---------------------------------------------------------------------------
__global__ __launch_bounds__(256) void k0_pack_w(const float* __restrict__ Wq,
                                                 const float* __restrict__ Wk,
                                                 unsigned short* __restrict__ WT) {
  __shared__ unsigned short tile[64][65];
  int bid = blockIdx.x;
  int dt = bid & 15, at = bid >> 4;
  int d0 = dt * 64, a0 = at * 64;
  int t = threadIdx.x;
  int col = t & 63, rbase = t >> 6;
#pragma unroll
  for (int r8 = 0; r8 < 16; ++r8) {
    int row = r8 * 4 + rbase;
    int dcat = d0 + row;
    float f = (dcat < 512) ? Wq[(size_t)dcat * 512 + a0 + col]
                           : Wk[(size_t)(dcat - 512) * 512 + a0 + col];
    tile[row][col] = f2bf(f);
  }
  __syncthreads();
#pragma unroll
  for (int r8 = 0; r8 < 16; ++r8) {
    int arow = r8 * 4 + rbase;
    WT[(size_t)(a0 + arow) * 1024 + d0 + col] = tile[col][arow];
  }
}

// ---------------------------------------------------------------------------
// K1: scores. BM=128, BN=512 (full N), BK=32, 32 phases.
// 512 threads = 8 waves; wave w owns cols [w*64, w*64+64): wave-tile 128x64
// (8 m-frags x 4 n-frags, acc = 128 VGPR -> 2 waves/SIMD, m201 regime).
// Counted-vmcnt pipeline, NO vmcnt(0) in the main loop:
//   phase p: stageB(p+1) | issueA(p+2)->regs | frags(p) | 32 MFMA |
//            writeA(p+1) (write-late, T14) | vmcnt(2) lgkm(0) | s_barrier
// A-loads survive the barrier (2 left in flight); B gloads get a full MFMA
// phase of cover. Tail phases 30/31 peeled (different vmcnt counts).
// LDS swizzle: 64B rows, 4x16B chunks, chunk' = chunk ^ ((row>>1)&3).
// ---------------------------------------------------------------------------
__global__ __launch_bounds__(512, 2) void k1_scores(
    const float* __restrict__ Q, const float* __restrict__ K,
    const unsigned short* __restrict__ WT, const float* __restrict__ Wsv,
    float* __restrict__ score) {
  __shared__ unsigned short Al[2][128 * 32];   // 2 x 8 KiB
  __shared__ unsigned short Bl[2][512 * 32];   // 2 x 32 KiB

  const int t = threadIdx.x;
  const int lane = t & 63, w = t >> 6;
  const int frow = lane & 15, fsl = lane >> 4;
  const int row0 = (int)blockIdx.x * 128;

  // A staging: thread handles row ar, 8 floats at cols ak..ak+7 (one 16B chunk)
  const int ar = t >> 2, ak = (t & 3) * 8;
  const int abyte = ar * 64 + (((t & 3) ^ ((ar >> 1) & 3)) * 16);

  float4 rA0[2], rA1[2];

  auto issueA = [&](int p, float4* r) {
    const float* src = (p < 16) ? Q : K;
    const float* ap = src + (size_t)(row0 + ar) * 512 + ((p * 32) & 511) + ak;
    r[0] = *(const float4*)(ap);
    r[1] = *(const float4*)(ap + 4);
  };
  auto writeA = [&](const float4* r, int buf) {
    uint4 d;
    d.x = f2bf(r[0].x) | ((unsigned)f2bf(r[0].y) << 16);
    d.y = f2bf(r[0].z) | ((unsigned)f2bf(r[0].w) << 16);
    d.z = f2bf(r[1].x) | ((unsigned)f2bf(r[1].y) << 16);
    d.w = f2bf(r[1].z) | ((unsigned)f2bf(r[1].w) << 16);
    *(uint4*)((char*)&Al[buf][0] + abyte) = d;
  };
  auto stageB = [&](int p, int buf) {
#pragma unroll
    for (int q = 0; q < 4; ++q) {
      int pc = (w * 4 + q) * 64 + lane;        // 16B-chunk index
      int row = pc >> 2;
      int sl = (pc & 3) ^ ((row >> 1) & 3);    // inverse-swizzled source slot
      const char* g = (const char*)WT + (size_t)row * 2048 + p * 64 + sl * 16;
      gload_lds16(g, (char*)&Bl[buf][0] + (size_t)(w * 4 + q) * 1024);
    }
  };

  f32x4 acc[8][4];
#pragma unroll
  for (int m = 0; m < 8; ++m)
#pragma unroll
    for (int n = 0; n < 4; ++n) acc[m][n] = (f32x4){0.f, 0.f, 0.f, 0.f};

  const int ch = (fsl ^ ((frow >> 1) & 3)) * 16;

  auto doMfma = [&](int CUR) {
    bf16x8 af[8], bfr[4];
#pragma unroll
    for (int m = 0; m < 8; ++m)
      af[m] = *(const bf16x8*)((const char*)&Al[CUR][0] + (m * 16 + frow) * 64 + ch);
#pragma unroll
    for (int n = 0; n < 4; ++n)
      bfr[n] = *(const bf16x8*)((const char*)&Bl[CUR][0] + (w * 64 + n * 16 + frow) * 64 + ch);
    __builtin_amdgcn_s_setprio(1);
#pragma unroll
    for (int m = 0; m < 8; ++m)
#pragma unroll
      for (int n = 0; n < 4; ++n)
        acc[m][n] = __builtin_amdgcn_mfma_f32_16x16x32_bf16(af[m], bfr[n], acc[m][n], 0, 0, 0);
    __builtin_amdgcn_s_setprio(0);
  };

  // ---- prologue: tile 0 staged; A(1) left in flight across the barrier ----
  issueA(0, rA0);
  stageB(0, 0);
  __builtin_amdgcn_sched_barrier(0);
  issueA(1, rA1);
  writeA(rA0, 0);                       // compiler waits its own A(0) loads
  asm volatile("s_waitcnt vmcnt(2) lgkmcnt(0)" ::: "memory");
  __builtin_amdgcn_s_barrier();

  // ---- main loop: phases 0..29 ----
  auto phase = [&](int p, int CUR, float4* rCur, const float4* rNext) {
    stageB(p + 1, CUR ^ 1);
    __builtin_amdgcn_sched_barrier(0);
    issueA(p + 2, rCur);
    doMfma(CUR);
    writeA(rNext, CUR ^ 1);             // A(p+1), write-late
    asm volatile("s_waitcnt vmcnt(2) lgkmcnt(0)" ::: "memory");
    __builtin_amdgcn_s_barrier();
  };

  for (int kt2 = 0; kt2 < 15; ++kt2) {
    phase(2 * kt2 + 0, 0, rA0, rA1);
    phase(2 * kt2 + 1, 1, rA1, rA0);
  }

  // ---- peeled tail: phase 30 (no A issue), phase 31 (compute only) ----
  stageB(31, 1);
  doMfma(0);
  writeA(rA1, 1);                       // A(31)
  asm volatile("s_waitcnt vmcnt(0) lgkmcnt(0)" ::: "memory");
  __builtin_amdgcn_s_barrier();
  doMfma(1);

  // ---- epilogue: tanh * Ws, reduce over all 512 cols ----
  float wsv[4];
#pragma unroll
  for (int n = 0; n < 4; ++n) wsv[n] = Wsv[w * 64 + n * 16 + frow];
  __syncthreads();                      // safe to alias Al for scw
  float* scw = (float*)&Al[0][0];       // [8][128]
#pragma unroll
  for (int m = 0; m < 8; ++m) {
#pragma unroll
    for (int ii = 0; ii < 4; ++ii) {
      float s = 0.f;
#pragma unroll
      for (int n = 0; n < 4; ++n)
        s += fast_tanh(acc[m][n][ii]) * wsv[n];
      s += __shfl_xor(s, 1);
      s += __shfl_xor(s, 2);
      s += __shfl_xor(s, 4);
      s += __shfl_xor(s, 8);
      if (frow == 0) scw[w * 128 + m * 16 + fsl * 4 + ii] = s;
    }
  }
  __syncthreads();
  if (t < 128) {
    float s = 0.f;
#pragma unroll
    for (int ww = 0; ww < 8; ++ww) s += scw[ww * 128 + t];
    score[row0 + t] = s;
  }
}

// ---------------------------------------------------------------------------
// K2: softmax over S=2048 per batch. Writes attention weights to d_out+B*A.
// ---------------------------------------------------------------------------
__global__ __launch_bounds__(256) void k2_softmax(const float* __restrict__ score,
                                                  float* __restrict__ outw) {
  int b = blockIdx.x, t = threadIdx.x;
  int lane = t & 63, wave = t >> 6;
  __shared__ float red[4], red2[4];
  float v[8];
  float mx = -1e30f;
#pragma unroll
  for (int e = 0; e < 8; ++e) {
    float p = score[(size_t)b * S_ + e * 256 + t];
    v[e] = p;
    mx = fmaxf(mx, p);
  }
  for (int off = 1; off < 64; off <<= 1) mx = fmaxf(mx, __shfl_xor(mx, off));
  if (lane == 0) red[wave] = mx;
  __syncthreads();
  mx = fmaxf(fmaxf(red[0], red[1]), fmaxf(red[2], red[3]));
  float sum = 0.f;
#pragma unroll
  for (int e = 0; e < 8; ++e) { v[e] = expf(v[e] - mx); sum += v[e]; }
  for (int off = 1; off < 64; off <<= 1) sum += __shfl_xor(sum, off);
  if (lane == 0) red2[wave] = sum;
  __syncthreads();
  sum = red2[0] + red2[1] + red2[2] + red2[3];
  float inv = 1.f / sum;
#pragma unroll
  for (int e = 0; e < 8; ++e)
    outw[(size_t)b * S_ + e * 256 + t] = v[e] * inv;
}

// ---------------------------------------------------------------------------
// K3: u_part[sc][b][d-half] = sum over 128 s of w[b,s]*value[b,s,d]. fp32.
// ---------------------------------------------------------------------------
__global__ __launch_bounds__(256) void k3_vsum(const float* __restrict__ value,
                                               const float* __restrict__ w,
                                               float* __restrict__ upart) {
  int bid = blockIdx.x;
  int dh = bid & 1, sc = (bid >> 1) & 15, b = bid >> 5;
  int t = threadIdx.x;
  int dg = t & 63, sg = t >> 6;
  __shared__ float wl[128];
  __shared__ f32x4 red[4][64];
  int s0 = sc * 128;
  if (t < 128) wl[t] = w[(size_t)b * S_ + s0 + t];
  __syncthreads();
  const float* vp = value + ((size_t)b * S_ + s0) * 512 + dh * 256 + dg * 4;
  f32x4 a = (f32x4){0.f, 0.f, 0.f, 0.f};
  for (int s = sg; s < 128; s += 4) {
    float4 v4 = *(const float4*)(vp + (size_t)s * 512);
    float ws = wl[s];
    a[0] += ws * v4.x; a[1] += ws * v4.y; a[2] += ws * v4.z; a[3] += ws * v4.w;
  }
  red[sg][dg] = a;
  __syncthreads();
  if (sg == 0) {
    f32x4 r = red[0][dg] + red[1][dg] + red[2][dg] + red[3][dg];
    float* dst = upart + (size_t)(sc * 16 + b) * 512 + dh * 256 + dg * 4;
    dst[0] = r[0]; dst[1] = r[1]; dst[2] = r[2]; dst[3] = r[3];
  }
}

// ---------------------------------------------------------------------------
// K4: context[b,a] = sum_d u[b,d] * Wv[d,a]. fp32.
// ---------------------------------------------------------------------------
__global__ __launch_bounds__(512) void k4_ctx(const float* __restrict__ upart,
                                              const float* __restrict__ Wv,
                                              float* __restrict__ out) {
  int b = blockIdx.x, t = threadIdx.x;
  __shared__ float ul[512];
  float u = 0.f;
#pragma unroll
  for (int c = 0; c < 16; ++c) u += upart[(size_t)(c * 16 + b) * 512 + t];
  ul[t] = u;
  __syncthreads();
  float acc = 0.f;
#pragma unroll 8
  for (int d = 0; d < 512; ++d) acc += ul[d] * Wv[(size_t)d * 512 + t];
  out[(size_t)b * 512 + t] = acc;
}

// ---------------------------------------------------------------------------
extern "C" void kernel_launch(void* const* d_in, const int* in_sizes, int n_in,
                              void* d_out, int out_size, void* d_ws, size_t ws_size,
                              hipStream_t stream) {
  const float* Q  = (const float*)d_in[0];
  const float* Kk = (const float*)d_in[1];
  const float* V  = (const float*)d_in[2];
  const float* Wq = (const float*)d_in[3];
  const float* Wk = (const float*)d_in[4];
  const float* Wv = (const float*)d_in[5];
  const float* Ws = (const float*)d_in[6];
  float* out = (float*)d_out;

  char* ws = (char*)d_ws;
  unsigned short* WT = (unsigned short*)ws;                        // 1 MiB
  float* score = (float*)(ws + (1 << 20));                         // 128 KiB
  float* upart = (float*)(ws + (1 << 20) + (512 << 10));           // 512 KiB

  float* outw = out + B_ * A_;   // attention weights region [B*S]

  k0_pack_w<<<dim3(128), dim3(256), 0, stream>>>(Wq, Wk, WT);
  k1_scores<<<dim3(256), dim3(512), 0, stream>>>(Q, Kk, WT, Ws, score);
  k2_softmax<<<dim3(16), dim3(256), 0, stream>>>(score, outw);
  k3_vsum<<<dim3(512), dim3(256), 0, stream>>>(V, outw, upart);
  k4_ctx<<<dim3(16), dim3(512), 0, stream>>>(upart, Wv, out);
}